// Round 12
// baseline (52.220 us; speedup 1.0000x reference)
//
#include <hip/hip_runtime.h>

#define DISP_W 1.0f
#define MAT_W  0.1f
#define CD_W   0.5f

typedef _Float16 half8 __attribute__((ext_vector_type(8)));
typedef float f32x16 __attribute__((ext_vector_type(16)));
typedef float f32x4  __attribute__((ext_vector_type(4)));

constexpr int BB = 4;           // batch
constexpr int NN = 8192;        // points per cloud
constexpr int THREADS = 256;    // 4 waves
constexpr int IB = 128;         // A-rows per block = 4 waves x 32
constexpr int JR = 1024;        // B-cols per LDS stage
constexpr int NIB = NN / IB;    // 64
constexpr int NJB = NN / JR;    // 8 stages (full sweep per block)
constexpr int NCHUNK = JR / 32; // 32
constexpr int NPTS = 2 * BB * NN;       // 65536
constexpr int GRID = 2 * BB * NIB;      // 512 = 2 blocks/CU, one dispatch round
constexpr int RSTRIDE = 36;     // epilogue scratch row stride in floats (144 B)

// Verified K=16 MFMA layout (rounds 3-11, absmax 0.0):
//  A: [xh yh zh  xh yh zh  xl yl | zl ch cl 1 1 0 0 0]
//  B: [uxh uyh uzh uxl uyl uzl uxh uyh | uzh 1 1 ch cl 0 0 0]  (u = -2*pos)
// dot = -2 a.b (hi/lo compensated) + ca + cb = |a-b|^2 (~f32 precision).

__global__ __launch_bounds__(256)
void build_frags(const float* __restrict__ pred_disp,
                 const float* __restrict__ target_disp,
                 const float* __restrict__ tmpl,
                 half8* __restrict__ fragA,      // [cloud][b][n][2] (hi,lo)
                 half8* __restrict__ fragBhi,    // [cloud][b][n]
                 half8* __restrict__ fragBlo,
                 float* __restrict__ out)
{
    int p = blockIdx.x * 256 + threadIdx.x;     // 0..65535
    if (p == 0) out[0] = 0.0f;                  // graph-replay re-zero (no memset dispatch)
    int c = p >> 15;
    int b = (p >> 13) & (BB - 1);
    int n = p & (NN - 1);

    const float* dp = (c ? target_disp : pred_disp) + (size_t)b * NN * 3;
    const float* tp = tmpl + (size_t)b * NN * 3;

    int n3 = n * 3;
    float x = tp[n3 + 0] + dp[n3 + 0];
    float y = tp[n3 + 1] + dp[n3 + 1];
    float z = tp[n3 + 2] + dp[n3 + 2];
    float cc = fmaf(x, x, fmaf(y, y, z * z));

    _Float16 xh = (_Float16)x;  _Float16 xl = (_Float16)(x - (float)xh);
    _Float16 yh = (_Float16)y;  _Float16 yl = (_Float16)(y - (float)yh);
    _Float16 zh = (_Float16)z;  _Float16 zl = (_Float16)(z - (float)zh);
    _Float16 ch = (_Float16)cc; _Float16 cl = (_Float16)(cc - (float)ch);

    float ux = -2.0f * x, uy = -2.0f * y, uz = -2.0f * z;
    _Float16 uxh = (_Float16)ux; _Float16 uxl = (_Float16)(ux - (float)uxh);
    _Float16 uyh = (_Float16)uy; _Float16 uyl = (_Float16)(uy - (float)uyh);
    _Float16 uzh = (_Float16)uz; _Float16 uzl = (_Float16)(uz - (float)uzh);

    const _Float16 one  = (_Float16)1.0f;
    const _Float16 zero = (_Float16)0.0f;

    half8 aHi = {xh, yh, zh, xh, yh, zh, xl, yl};
    half8 aLo = {zl, ch, cl, one, one, zero, zero, zero};
    half8 bHi = {uxh, uyh, uzh, uxl, uyl, uzl, uxh, uyh};
    half8 bLo = {uzh, one, one, ch, cl, zero, zero, zero};

    fragA[(size_t)p * 2 + 0] = aHi;
    fragA[(size_t)p * 2 + 1] = aLo;
    fragBhi[p] = bHi;
    fragBlo[p] = bLo;
}

__global__ __launch_bounds__(THREADS, 2)   // 256-reg budget: MFMA accs stay in arch VGPRs
void chamfer_mfma(const half8* __restrict__ fragA,
                  const half8* __restrict__ fragBhi,
                  const half8* __restrict__ fragBlo,
                  float* __restrict__ rowmin)
{
    // 32 KB LDS: sBhi/sBlo staging; region reused as transpose scratch at the end
    __shared__ __align__(16) char lds_raw[32768];
    half8* sBhi = (half8*)lds_raw;            // 16 KB
    half8* sBlo = (half8*)(lds_raw + 16384);  // 16 KB

    int bx = blockIdx.x;
    int iBlk = bx & (NIB - 1);
    int b    = (bx >> 6) & (BB - 1);
    int dir  = bx >> 8;
    int cA = dir, cB = dir ^ 1;

    const int tid  = threadIdx.x;
    const int lane = tid & 63;
    const int w    = tid >> 6;
    const int hi   = lane >> 5;
    const int li   = lane & 31;

    // ---- one A fragment per wave, loaded ONCE, reused across all 8 stages ----
    int i0 = iBlk * IB + w * 32 + li;
    half8 aF = fragA[(((size_t)cA * BB + b) * NN + i0) * 2 + hi];

    size_t pB = ((size_t)cB * BB + b) * NN;
    const half8* gHi = fragBhi + pB;
    const half8* gLo = fragBlo + pB;

    f32x16 kZero = {0.f,0.f,0.f,0.f, 0.f,0.f,0.f,0.f, 0.f,0.f,0.f,0.f, 0.f,0.f,0.f,0.f};
    float rm[16];
    #pragma unroll
    for (int r = 0; r < 16; ++r) rm[r] = 1.0e30f;

    // ---- persistent sweep: all 8 j-stages through one LDS buffer ----
    for (int j = 0; j < NJB; ++j) {
        const half8* srcHi = gHi + (size_t)j * JR;
        const half8* srcLo = gLo + (size_t)j * JR;
        #pragma unroll
        for (int t = 0; t < JR / THREADS; ++t) {
            int idx = t * THREADS + tid;
            sBhi[idx] = srcHi[idx];
            sBlo[idx] = srcLo[idx];
        }
        __syncthreads();

        const half8* baseB = hi ? sBlo : sBhi;
        // 4 tiles in flight sharing aF; min3 fold = 8 VALU per tile
        #pragma unroll 2
        for (int c = 0; c < NCHUNK; c += 4) {
            half8 b0 = baseB[(c + 0) * 32 + li];
            half8 b1 = baseB[(c + 1) * 32 + li];
            half8 b2 = baseB[(c + 2) * 32 + li];
            half8 b3 = baseB[(c + 3) * 32 + li];
            f32x16 a0 = __builtin_amdgcn_mfma_f32_32x32x16_f16(aF, b0, kZero, 0, 0, 0);
            f32x16 a1 = __builtin_amdgcn_mfma_f32_32x32x16_f16(aF, b1, kZero, 0, 0, 0);
            f32x16 a2 = __builtin_amdgcn_mfma_f32_32x32x16_f16(aF, b2, kZero, 0, 0, 0);
            f32x16 a3 = __builtin_amdgcn_mfma_f32_32x32x16_f16(aF, b3, kZero, 0, 0, 0);
            #pragma unroll
            for (int r = 0; r < 16; ++r)
                rm[r] = fminf(rm[r], fminf(a0[r], a1[r]));
            #pragma unroll
            for (int r = 0; r < 16; ++r)
                rm[r] = fminf(rm[r], fminf(a2[r], a3[r]));
        }
        __syncthreads();   // all waves done reading before next stage overwrites
    }

    // ---- epilogue (once per block): LDS transpose, coalesced store ----
    float* scr = (float*)lds_raw;
    // write: reg r of lane (hi,li) is (row=(r&3)+8*(r>>2)+4*hi, col=li)
    int wbase = w * (32 * RSTRIDE);                 // per-wave 4608 B region
    int cbase = wbase + hi * 4 * RSTRIDE + li;
    #pragma unroll
    for (int r = 0; r < 16; ++r)
        scr[cbase + ((r & 3) + 8 * (r >> 2)) * RSTRIDE] = rm[r];
    __syncthreads();

    // read row (lane&31) back: 8x ds_read_b128, fold 32 -> 1
    const f32x4* rp = (const f32x4*)&scr[wbase + (lane & 31) * RSTRIDE];
    f32x4 q0 = rp[0], q1 = rp[1], q2 = rp[2], q3 = rp[3];
    f32x4 q4 = rp[4], q5 = rp[5], q6 = rp[6], q7 = rp[7];
    f32x4 m4;
    #pragma unroll
    for (int k = 0; k < 4; ++k)
        m4[k] = fminf(fminf(fminf(q0[k], q1[k]), fminf(q2[k], q3[k])),
                      fminf(fminf(q4[k], q5[k]), fminf(q6[k], q7[k])));
    float m = fminf(fminf(m4[0], m4[1]), fminf(m4[2], m4[3]));

    if (lane < 32) {
        size_t base = ((size_t)(dir * BB + b)) * NN + (size_t)iBlk * IB + w * 32;
        rowmin[base + lane] = m;    // FINAL row-min (no jBlk partials anymore)
    }
}

__global__ __launch_bounds__(256)
void final_reduce(const float* __restrict__ pred_disp,
                  const float* __restrict__ target_disp,
                  const float* __restrict__ pred_mat,
                  const float* __restrict__ target_mat,
                  const float* __restrict__ rowmin,
                  float* __restrict__ out)
{
    const int NDISP = BB * NN * 3;   // 98304
    const int NROWS = 2 * BB * NN;   // 65536

    int gtid = blockIdx.x * blockDim.x + threadIdx.x;
    int gstride = gridDim.x * blockDim.x;

    float dsum = 0.0f;
    for (int i = gtid; i < NDISP; i += gstride)
        dsum += fabsf(pred_disp[i] - target_disp[i]);

    float msum = 0.0f;
    for (int t = gtid; t < NROWS; t += gstride)
        msum += fmaxf(rowmin[t], 0.0f);   // clamp tiny negatives from dot-form

    float acc = dsum * (DISP_W / (float)NDISP)
              + msum * (CD_W / (float)(BB * NN));

    if (gtid < 2 * BB) {
        float d = pred_mat[gtid] - target_mat[gtid];
        acc += d * d * (MAT_W / (float)(2 * BB));
    }

    for (int off = 32; off > 0; off >>= 1)
        acc += __shfl_down(acc, off, 64);

    __shared__ float wsum[4];
    if ((threadIdx.x & 63) == 0) wsum[threadIdx.x >> 6] = acc;
    __syncthreads();
    if (threadIdx.x == 0)
        atomicAdd(out, wsum[0] + wsum[1] + wsum[2] + wsum[3]);
}

extern "C" void kernel_launch(void* const* d_in, const int* in_sizes, int n_in,
                              void* d_out, int out_size, void* d_ws, size_t ws_size,
                              hipStream_t stream) {
    const float* pred_disp   = (const float*)d_in[0];
    const float* pred_mat    = (const float*)d_in[1];
    const float* target_disp = (const float*)d_in[2];
    const float* target_mat  = (const float*)d_in[3];
    const float* tmpl        = (const float*)d_in[4];

    // ws layout:
    //   fragA   : NPTS*2 half8 = 2 MB
    //   fragBhi : NPTS   half8 = 1 MB
    //   fragBlo : NPTS   half8 = 1 MB
    //   rowmin  : 2*BB*NN floats = 256 KB  (every slot written exactly once)
    half8* fragA   = (half8*)d_ws;
    half8* fragBhi = fragA + (size_t)NPTS * 2;
    half8* fragBlo = fragBhi + NPTS;
    float* rowmin  = (float*)(fragBlo + NPTS);
    float* out = (float*)d_out;

    build_frags<<<NPTS / 256, 256, 0, stream>>>(pred_disp, target_disp, tmpl,
                                                fragA, fragBhi, fragBlo, out);
    chamfer_mfma<<<GRID, THREADS, 0, stream>>>(fragA, fragBhi, fragBlo, rowmin);
    final_reduce<<<256, 256, 0, stream>>>(pred_disp, target_disp, pred_mat, target_mat,
                                          rowmin, out);
}

// Round 13
// 48.339 us; speedup vs baseline: 1.0803x; 1.0803x over previous
//
#include <hip/hip_runtime.h>

#define DISP_W 1.0f
#define MAT_W  0.1f
#define CD_W   0.5f

typedef _Float16 half8 __attribute__((ext_vector_type(8)));
typedef float f32x16 __attribute__((ext_vector_type(16)));
typedef float f32x4  __attribute__((ext_vector_type(4)));

constexpr int BB = 4;           // batch
constexpr int NN = 8192;        // points per cloud
constexpr int THREADS = 256;    // 4 waves
constexpr int IB = 128;         // A-rows per block = 4 waves x 32
constexpr int JR = 1024;        // B-cols per block
constexpr int NIB = NN / IB;    // 64
constexpr int NJB = NN / JR;    // 8
constexpr int NCHUNK = JR / 32; // 32
constexpr int NPTS = 2 * BB * NN;          // 65536
constexpr int GRID = 2 * BB * NIB * NJB;   // 4096
constexpr int RSTRIDE = 36;     // epilogue scratch row stride in floats (144 B)

// Verified K=16 MFMA layout (rounds 3-12, absmax 0.0):
//  A: [xh yh zh  xh yh zh  xl yl | zl ch cl 1 1 0 0 0]
//  B: [uxh uyh uzh uxl uyl uzl uxh uyh | uzh 1 1 ch cl 0 0 0]  (u = -2*pos)
// dot = -2 a.b (hi/lo compensated) + ca + cb = |a-b|^2 (~f32 precision).

__global__ __launch_bounds__(256)
void build_frags(const float* __restrict__ pred_disp,
                 const float* __restrict__ target_disp,
                 const float* __restrict__ tmpl,
                 half8* __restrict__ fragA,      // [cloud][b][n][2] (hi,lo)
                 half8* __restrict__ fragBhi,    // [cloud][b][n]
                 half8* __restrict__ fragBlo,
                 float* __restrict__ out)
{
    int p = blockIdx.x * 256 + threadIdx.x;     // 0..65535
    if (p == 0) out[0] = 0.0f;                  // graph-replay re-zero (no memset dispatch)
    int c = p >> 15;
    int b = (p >> 13) & (BB - 1);
    int n = p & (NN - 1);

    const float* dp = (c ? target_disp : pred_disp) + (size_t)b * NN * 3;
    const float* tp = tmpl + (size_t)b * NN * 3;

    int n3 = n * 3;
    float x = tp[n3 + 0] + dp[n3 + 0];
    float y = tp[n3 + 1] + dp[n3 + 1];
    float z = tp[n3 + 2] + dp[n3 + 2];
    float cc = fmaf(x, x, fmaf(y, y, z * z));

    _Float16 xh = (_Float16)x;  _Float16 xl = (_Float16)(x - (float)xh);
    _Float16 yh = (_Float16)y;  _Float16 yl = (_Float16)(y - (float)yh);
    _Float16 zh = (_Float16)z;  _Float16 zl = (_Float16)(z - (float)zh);
    _Float16 ch = (_Float16)cc; _Float16 cl = (_Float16)(cc - (float)ch);

    float ux = -2.0f * x, uy = -2.0f * y, uz = -2.0f * z;
    _Float16 uxh = (_Float16)ux; _Float16 uxl = (_Float16)(ux - (float)uxh);
    _Float16 uyh = (_Float16)uy; _Float16 uyl = (_Float16)(uy - (float)uyh);
    _Float16 uzh = (_Float16)uz; _Float16 uzl = (_Float16)(uz - (float)uzh);

    const _Float16 one  = (_Float16)1.0f;
    const _Float16 zero = (_Float16)0.0f;

    half8 aHi = {xh, yh, zh, xh, yh, zh, xl, yl};
    half8 aLo = {zl, ch, cl, one, one, zero, zero, zero};
    half8 bHi = {uxh, uyh, uzh, uxl, uyl, uzl, uxh, uyh};
    half8 bLo = {uzh, one, one, ch, cl, zero, zero, zero};

    fragA[(size_t)p * 2 + 0] = aHi;
    fragA[(size_t)p * 2 + 1] = aLo;
    fragBhi[p] = bHi;
    fragBlo[p] = bLo;
}

__global__ __launch_bounds__(THREADS, 2)   // 256-reg budget: keep MFMA accs in arch VGPRs
void chamfer_mfma(const half8* __restrict__ fragA,
                  const half8* __restrict__ fragBhi,
                  const half8* __restrict__ fragBlo,
                  float* __restrict__ rowpart)
{
    // 32 KB LDS: sBhi/sBlo during main loop; region reused as transpose scratch
    __shared__ __align__(16) char lds_raw[32768];
    half8* sBhi = (half8*)lds_raw;            // 16 KB
    half8* sBlo = (half8*)(lds_raw + 16384);  // 16 KB

    int bx = blockIdx.x;
    int jBlk = bx & (NJB - 1);
    int iBlk = (bx >> 3) & (NIB - 1);
    int b    = (bx >> 9) & (BB - 1);
    int dir  = bx >> 11;
    int cA = dir, cB = dir ^ 1;

    const int tid  = threadIdx.x;
    const int lane = tid & 63;
    const int w    = tid >> 6;
    const int hi   = lane >> 5;
    const int li   = lane & 31;

    // ---- stage B fragments (split hi/lo arrays: measured 0 bank conflicts) ----
    size_t pB = ((size_t)cB * BB + b) * NN + (size_t)jBlk * JR;
    const half8* gHi = fragBhi + pB;
    const half8* gLo = fragBlo + pB;
    #pragma unroll
    for (int t = 0; t < JR / THREADS; ++t) {
        int idx = t * THREADS + tid;
        sBhi[idx] = gHi[idx];
        sBlo[idx] = gLo[idx];
    }

    // ---- one A fragment per wave (32 rows; lanes l and l+32 share a point) ----
    int i0 = iBlk * IB + w * 32 + li;
    half8 aF = fragA[(((size_t)cA * BB + b) * NN + i0) * 2 + hi];

    __syncthreads();

    f32x16 kZero = {0.f,0.f,0.f,0.f, 0.f,0.f,0.f,0.f, 0.f,0.f,0.f,0.f, 0.f,0.f,0.f,0.f};
    const half8* baseB = hi ? sBlo : sBhi;
    float rm[16];
    #pragma unroll
    for (int r = 0; r < 16; ++r) rm[r] = 1.0e30f;

    // 2 tiles in flight sharing aF; single min3 fold chain:
    // rm = min3(rm, a0, a1) -> 8 VALU per tile, only a0/a1/rm live (VGPR-form)
    #pragma unroll 4
    for (int c = 0; c < NCHUNK; c += 2) {
        half8 b0 = baseB[(c + 0) * 32 + li];
        half8 b1 = baseB[(c + 1) * 32 + li];
        f32x16 a0 = __builtin_amdgcn_mfma_f32_32x32x16_f16(aF, b0, kZero, 0, 0, 0);
        f32x16 a1 = __builtin_amdgcn_mfma_f32_32x32x16_f16(aF, b1, kZero, 0, 0, 0);
        #pragma unroll
        for (int r = 0; r < 16; ++r)
            rm[r] = fminf(rm[r], fminf(a0[r], a1[r]));   // clang fuses -> v_min3_f32
    }

    // ---- epilogue: LDS transpose (reuse staging region), coalesced store ----
    __syncthreads();   // all waves done reading sB
    float* scr = (float*)lds_raw;
    // write: reg r of lane (hi,li) is (row=(r&3)+8*(r>>2)+4*hi, col=li)
    int wbase = w * (32 * RSTRIDE);                 // per-wave 4608 B region
    int cbase = wbase + hi * 4 * RSTRIDE + li;
    #pragma unroll
    for (int r = 0; r < 16; ++r)
        scr[cbase + ((r & 3) + 8 * (r >> 2)) * RSTRIDE] = rm[r];
    __syncthreads();

    // read row (lane&31) back: 8x ds_read_b128, fold 32 -> 1
    const f32x4* rp = (const f32x4*)&scr[wbase + (lane & 31) * RSTRIDE];
    f32x4 q0 = rp[0], q1 = rp[1], q2 = rp[2], q3 = rp[3];
    f32x4 q4 = rp[4], q5 = rp[5], q6 = rp[6], q7 = rp[7];
    f32x4 m4;
    #pragma unroll
    for (int k = 0; k < 4; ++k)
        m4[k] = fminf(fminf(fminf(q0[k], q1[k]), fminf(q2[k], q3[k])),
                      fminf(fminf(q4[k], q5[k]), fminf(q6[k], q7[k])));
    float m = fminf(fminf(m4[0], m4[1]), fminf(m4[2], m4[3]));

    if (lane < 32) {
        size_t base = ((size_t)(dir * BB + b) * NJB + jBlk) * NN
                    + (size_t)iBlk * IB + w * 32;
        rowpart[base + lane] = m;
    }
}

__global__ __launch_bounds__(256)
void final_reduce(const float* __restrict__ pred_disp,
                  const float* __restrict__ target_disp,
                  const float* __restrict__ pred_mat,
                  const float* __restrict__ target_mat,
                  const float* __restrict__ rowpart,
                  float* __restrict__ out)
{
    const int NDISP = BB * NN * 3;   // 98304
    const int NROWS = 2 * BB * NN;   // 65536

    int gtid = blockIdx.x * blockDim.x + threadIdx.x;
    int gstride = gridDim.x * blockDim.x;

    float dsum = 0.0f;
    for (int i = gtid; i < NDISP; i += gstride)
        dsum += fabsf(pred_disp[i] - target_disp[i]);

    float msum = 0.0f;
    for (int t = gtid; t < NROWS; t += gstride) {
        int db = t >> 13;            // dir*BB + b
        int i  = t & (NN - 1);
        const float* p = rowpart + (size_t)db * NJB * NN + i;
        float m = 1.0e30f;
        #pragma unroll
        for (int jb = 0; jb < NJB; ++jb)
            m = fminf(m, p[(size_t)jb * NN]);
        msum += fmaxf(m, 0.0f);      // clamp tiny negatives from dot-form
    }

    float acc = dsum * (DISP_W / (float)NDISP)
              + msum * (CD_W / (float)(BB * NN));

    if (gtid < 2 * BB) {
        float d = pred_mat[gtid] - target_mat[gtid];
        acc += d * d * (MAT_W / (float)(2 * BB));
    }

    for (int off = 32; off > 0; off >>= 1)
        acc += __shfl_down(acc, off, 64);

    __shared__ float wsum[4];
    if ((threadIdx.x & 63) == 0) wsum[threadIdx.x >> 6] = acc;
    __syncthreads();
    if (threadIdx.x == 0)
        atomicAdd(out, wsum[0] + wsum[1] + wsum[2] + wsum[3]);
}

extern "C" void kernel_launch(void* const* d_in, const int* in_sizes, int n_in,
                              void* d_out, int out_size, void* d_ws, size_t ws_size,
                              hipStream_t stream) {
    const float* pred_disp   = (const float*)d_in[0];
    const float* pred_mat    = (const float*)d_in[1];
    const float* target_disp = (const float*)d_in[2];
    const float* target_mat  = (const float*)d_in[3];
    const float* tmpl        = (const float*)d_in[4];

    // ws layout:
    //   fragA   : NPTS*2 half8 = 2 MB
    //   fragBhi : NPTS   half8 = 1 MB
    //   fragBlo : NPTS   half8 = 1 MB
    //   rowpart : 2*BB*NJB*NN floats = 2 MB  (every slot written exactly once)
    half8* fragA   = (half8*)d_ws;
    half8* fragBhi = fragA + (size_t)NPTS * 2;
    half8* fragBlo = fragBhi + NPTS;
    float* rowpart = (float*)(fragBlo + NPTS);
    float* out = (float*)d_out;

    build_frags<<<NPTS / 256, 256, 0, stream>>>(pred_disp, target_disp, tmpl,
                                                fragA, fragBhi, fragBlo, out);
    chamfer_mfma<<<GRID, THREADS, 0, stream>>>(fragA, fragBhi, fragBlo, rowpart);
    final_reduce<<<256, 256, 0, stream>>>(pred_disp, target_disp, pred_mat, target_mat,
                                          rowpart, out);
}

// Round 14
// 35.577 us; speedup vs baseline: 1.4678x; 1.3587x over previous
//
#include <hip/hip_runtime.h>

#define DISP_W 1.0f
#define MAT_W  0.1f
#define CD_W   0.5f

typedef _Float16 half8 __attribute__((ext_vector_type(8)));
typedef float f32x16 __attribute__((ext_vector_type(16)));
typedef float f32x4  __attribute__((ext_vector_type(4)));

constexpr int BB = 4;           // batch
constexpr int NN = 8192;        // points per cloud
constexpr int THREADS = 256;    // 4 waves
constexpr int IB = 256;         // A-rows per block = 4 waves x 64 (2 frags/wave)
constexpr int JR = 1024;        // B-cols per block
constexpr int NIB = NN / IB;    // 32
constexpr int NJB = NN / JR;    // 8
constexpr int NCHUNK = JR / 32; // 32
constexpr int NPTS = 2 * BB * NN;          // 65536
constexpr int GRID = 2 * BB * NIB * NJB;   // 2048
constexpr int RSTRIDE = 36;     // epilogue scratch row stride in floats (144 B)

// Verified K=16 MFMA layout (rounds 3-13, absmax 0.0):
//  A: [xh yh zh  xh yh zh  xl yl | zl ch cl 1 1 0 0 0]
//  B: [uxh uyh uzh uxl uyl uzl uxh uyh | uzh 1 1 ch cl 0 0 0]  (u = -2*pos)
// dot = -2 a.b (hi/lo compensated) + ca + cb = |a-b|^2 (~f32 precision).

__global__ __launch_bounds__(256)
void build_frags(const float* __restrict__ pred_disp,
                 const float* __restrict__ target_disp,
                 const float* __restrict__ tmpl,
                 half8* __restrict__ fragA,      // [cloud][b][n][2] (hi,lo)
                 half8* __restrict__ fragBhi,    // [cloud][b][n]
                 half8* __restrict__ fragBlo,
                 float* __restrict__ out)
{
    int p = blockIdx.x * 256 + threadIdx.x;     // 0..65535
    if (p == 0) out[0] = 0.0f;                  // graph-replay re-zero (no memset dispatch)
    int c = p >> 15;
    int b = (p >> 13) & (BB - 1);
    int n = p & (NN - 1);

    const float* dp = (c ? target_disp : pred_disp) + (size_t)b * NN * 3;
    const float* tp = tmpl + (size_t)b * NN * 3;

    int n3 = n * 3;
    float x = tp[n3 + 0] + dp[n3 + 0];
    float y = tp[n3 + 1] + dp[n3 + 1];
    float z = tp[n3 + 2] + dp[n3 + 2];
    float cc = fmaf(x, x, fmaf(y, y, z * z));

    _Float16 xh = (_Float16)x;  _Float16 xl = (_Float16)(x - (float)xh);
    _Float16 yh = (_Float16)y;  _Float16 yl = (_Float16)(y - (float)yh);
    _Float16 zh = (_Float16)z;  _Float16 zl = (_Float16)(z - (float)zh);
    _Float16 ch = (_Float16)cc; _Float16 cl = (_Float16)(cc - (float)ch);

    float ux = -2.0f * x, uy = -2.0f * y, uz = -2.0f * z;
    _Float16 uxh = (_Float16)ux; _Float16 uxl = (_Float16)(ux - (float)uxh);
    _Float16 uyh = (_Float16)uy; _Float16 uyl = (_Float16)(uy - (float)uyh);
    _Float16 uzh = (_Float16)uz; _Float16 uzl = (_Float16)(uz - (float)uzh);

    const _Float16 one  = (_Float16)1.0f;
    const _Float16 zero = (_Float16)0.0f;

    half8 aHi = {xh, yh, zh, xh, yh, zh, xl, yl};
    half8 aLo = {zl, ch, cl, one, one, zero, zero, zero};
    half8 bHi = {uxh, uyh, uzh, uxl, uyl, uzl, uxh, uyh};
    half8 bLo = {uzh, one, one, ch, cl, zero, zero, zero};

    fragA[(size_t)p * 2 + 0] = aHi;
    fragA[(size_t)p * 2 + 1] = aLo;
    fragBhi[p] = bHi;
    fragBlo[p] = bLo;
}

__global__ __launch_bounds__(THREADS, 2)   // 256-reg budget: accs usable in place
void chamfer_mfma(const half8* __restrict__ fragA,
                  const half8* __restrict__ fragBhi,
                  const half8* __restrict__ fragBlo,
                  float* __restrict__ rowpart)
{
    // 32 KB LDS: sBhi/sBlo during main loop; region reused as transpose scratch
    __shared__ __align__(16) char lds_raw[32768];
    half8* sBhi = (half8*)lds_raw;            // 16 KB
    half8* sBlo = (half8*)(lds_raw + 16384);  // 16 KB

    int bx = blockIdx.x;
    int jBlk = bx & (NJB - 1);
    int iBlk = (bx >> 3) & (NIB - 1);
    int b    = (bx >> 8) & (BB - 1);
    int dir  = bx >> 10;
    int cA = dir, cB = dir ^ 1;

    const int tid  = threadIdx.x;
    const int lane = tid & 63;
    const int w    = tid >> 6;
    const int hi   = lane >> 5;
    const int li   = lane & 31;

    // ---- stage B fragments (split hi/lo arrays: measured 0 bank conflicts) ----
    size_t pB = ((size_t)cB * BB + b) * NN + (size_t)jBlk * JR;
    const half8* gHi = fragBhi + pB;
    const half8* gLo = fragBlo + pB;
    #pragma unroll
    for (int t = 0; t < JR / THREADS; ++t) {
        int idx = t * THREADS + tid;
        sBhi[idx] = gHi[idx];
        sBlo[idx] = gLo[idx];
    }

    // ---- two A fragments per wave (rows i0 and i0+32) sharing every B-read ----
    int i0 = iBlk * IB + w * 64 + li;
    size_t aBase = ((size_t)cA * BB + b) * NN;
    half8 aF0 = fragA[(aBase + i0) * 2 + hi];
    half8 aF1 = fragA[(aBase + i0 + 32) * 2 + hi];

    __syncthreads();

    f32x16 kZero = {0.f,0.f,0.f,0.f, 0.f,0.f,0.f,0.f, 0.f,0.f,0.f,0.f, 0.f,0.f,0.f,0.f};
    const half8* baseB = hi ? sBlo : sBhi;
    float rm0[16], rm1[16];
    #pragma unroll
    for (int r = 0; r < 16; ++r) { rm0[r] = 1.0e30f; rm1[r] = 1.0e30f; }

    // 1 ds_read feeds 2 MFMAs (half the LDS-pipe traffic); dual independent
    // plain-fmin chains read the accumulators in place (winner r11 pattern).
    #pragma unroll 4
    for (int c = 0; c < NCHUNK; ++c) {
        half8 b0 = baseB[c * 32 + li];
        f32x16 a0 = __builtin_amdgcn_mfma_f32_32x32x16_f16(aF0, b0, kZero, 0, 0, 0);
        f32x16 a1 = __builtin_amdgcn_mfma_f32_32x32x16_f16(aF1, b0, kZero, 0, 0, 0);
        #pragma unroll
        for (int r = 0; r < 16; ++r)
            rm0[r] = fminf(rm0[r], a0[r]);
        #pragma unroll
        for (int r = 0; r < 16; ++r)
            rm1[r] = fminf(rm1[r], a1[r]);
    }

    // ---- epilogue: two per-wave LDS-transpose passes, coalesced stores ----
    __syncthreads();   // all waves done reading sB before scratch reuse
    float* scr = (float*)lds_raw;
    int wbase = w * (32 * RSTRIDE);                 // per-wave 4608 B region
    int cbase = wbase + hi * 4 * RSTRIDE + li;
    size_t obase = ((size_t)(dir * BB + b) * NJB + jBlk) * NN
                 + (size_t)iBlk * IB + w * 64;

    // pass 0: rows i0 block (w*64 .. +32)
    #pragma unroll
    for (int r = 0; r < 16; ++r)
        scr[cbase + ((r & 3) + 8 * (r >> 2)) * RSTRIDE] = rm0[r];
    __syncthreads();
    {
        const f32x4* rp = (const f32x4*)&scr[wbase + (lane & 31) * RSTRIDE];
        f32x4 q0 = rp[0], q1 = rp[1], q2 = rp[2], q3 = rp[3];
        f32x4 q4 = rp[4], q5 = rp[5], q6 = rp[6], q7 = rp[7];
        f32x4 m4;
        #pragma unroll
        for (int k = 0; k < 4; ++k)
            m4[k] = fminf(fminf(fminf(q0[k], q1[k]), fminf(q2[k], q3[k])),
                          fminf(fminf(q4[k], q5[k]), fminf(q6[k], q7[k])));
        float m = fminf(fminf(m4[0], m4[1]), fminf(m4[2], m4[3]));
        if (lane < 32) rowpart[obase + lane] = m;
    }
    __syncthreads();

    // pass 1: rows i0+32 block
    #pragma unroll
    for (int r = 0; r < 16; ++r)
        scr[cbase + ((r & 3) + 8 * (r >> 2)) * RSTRIDE] = rm1[r];
    __syncthreads();
    {
        const f32x4* rp = (const f32x4*)&scr[wbase + (lane & 31) * RSTRIDE];
        f32x4 q0 = rp[0], q1 = rp[1], q2 = rp[2], q3 = rp[3];
        f32x4 q4 = rp[4], q5 = rp[5], q6 = rp[6], q7 = rp[7];
        f32x4 m4;
        #pragma unroll
        for (int k = 0; k < 4; ++k)
            m4[k] = fminf(fminf(fminf(q0[k], q1[k]), fminf(q2[k], q3[k])),
                          fminf(fminf(q4[k], q5[k]), fminf(q6[k], q7[k])));
        float m = fminf(fminf(m4[0], m4[1]), fminf(m4[2], m4[3]));
        if (lane < 32) rowpart[obase + 32 + lane] = m;
    }
}

__global__ __launch_bounds__(256)
void final_reduce(const float* __restrict__ pred_disp,
                  const float* __restrict__ target_disp,
                  const float* __restrict__ pred_mat,
                  const float* __restrict__ target_mat,
                  const float* __restrict__ rowpart,
                  float* __restrict__ out)
{
    const int NDISP = BB * NN * 3;   // 98304
    const int NROWS = 2 * BB * NN;   // 65536

    int gtid = blockIdx.x * blockDim.x + threadIdx.x;
    int gstride = gridDim.x * blockDim.x;

    float dsum = 0.0f;
    for (int i = gtid; i < NDISP; i += gstride)
        dsum += fabsf(pred_disp[i] - target_disp[i]);

    float msum = 0.0f;
    for (int t = gtid; t < NROWS; t += gstride) {
        int db = t >> 13;            // dir*BB + b
        int i  = t & (NN - 1);
        const float* p = rowpart + (size_t)db * NJB * NN + i;
        float m = 1.0e30f;
        #pragma unroll
        for (int jb = 0; jb < NJB; ++jb)
            m = fminf(m, p[(size_t)jb * NN]);
        msum += fmaxf(m, 0.0f);      // clamp tiny negatives from dot-form
    }

    float acc = dsum * (DISP_W / (float)NDISP)
              + msum * (CD_W / (float)(BB * NN));

    if (gtid < 2 * BB) {
        float d = pred_mat[gtid] - target_mat[gtid];
        acc += d * d * (MAT_W / (float)(2 * BB));
    }

    for (int off = 32; off > 0; off >>= 1)
        acc += __shfl_down(acc, off, 64);

    __shared__ float wsum[4];
    if ((threadIdx.x & 63) == 0) wsum[threadIdx.x >> 6] = acc;
    __syncthreads();
    if (threadIdx.x == 0)
        atomicAdd(out, wsum[0] + wsum[1] + wsum[2] + wsum[3]);
}

extern "C" void kernel_launch(void* const* d_in, const int* in_sizes, int n_in,
                              void* d_out, int out_size, void* d_ws, size_t ws_size,
                              hipStream_t stream) {
    const float* pred_disp   = (const float*)d_in[0];
    const float* pred_mat    = (const float*)d_in[1];
    const float* target_disp = (const float*)d_in[2];
    const float* target_mat  = (const float*)d_in[3];
    const float* tmpl        = (const float*)d_in[4];

    // ws layout:
    //   fragA   : NPTS*2 half8 = 2 MB
    //   fragBhi : NPTS   half8 = 1 MB
    //   fragBlo : NPTS   half8 = 1 MB
    //   rowpart : 2*BB*NJB*NN floats = 2 MB  (every slot written exactly once)
    half8* fragA   = (half8*)d_ws;
    half8* fragBhi = fragA + (size_t)NPTS * 2;
    half8* fragBlo = fragBhi + NPTS;
    float* rowpart = (float*)(fragBlo + NPTS);
    float* out = (float*)d_out;

    build_frags<<<NPTS / 256, 256, 0, stream>>>(pred_disp, target_disp, tmpl,
                                                fragA, fragBhi, fragBlo, out);
    chamfer_mfma<<<GRID, THREADS, 0, stream>>>(fragA, fragBhi, fragBlo, rowpart);
    final_reduce<<<256, 256, 0, stream>>>(pred_disp, target_disp, pred_mat, target_mat,
                                          rowpart, out);
}